// Round 14
// baseline (79.691 us; speedup 1.0000x reference)
//
#include <hip/hip_runtime.h>

#define EMB 64
#define DICT 512
#define HW 4096              // 64*64
#define NPTS (32 * HW)       // 131072
#define MOM 0.99f
#define OMOM 0.01f
#define EPSV 1e-5f

typedef float v4f __attribute__((ext_vector_type(4)));
typedef unsigned int uint;
typedef uint uint4v __attribute__((ext_vector_type(4)));
typedef short short8 __attribute__((ext_vector_type(8)));
typedef __bf16 bf16x8 __attribute__((ext_vector_type(8)));
typedef float f32x4 __attribute__((ext_vector_type(4)));

// ws layout (dword offsets)
#define WS_COMMIT 0
#define WS_COUNTS 64                      // 512
#define WS_ESUM   1024                    // 64*512
#define WS_ZERO_FLOATS 33792              // zeroed by vq_prep each call
#define WS_EE     33792                   // 512 (fp32 ||e||^2)
#define WS_EHG    34320                   // 4 tiles * 4160 (packed bf16-hi E)
#define WS_IDS    67600                   // 131072 ints (natural pixel order)

#define PS 520      // plane stride in dwords: 130 rows x 4 dwords
#define TB 4160     // E tile blob: 8 planes (kh*4+g)

#define ESCALE 65536.0f
#define EINV   (1.0f / 65536.0f)

__device__ __forceinline__ uint bf16rne(float x) {
    uint u = __float_as_uint(x);
    return (u + 0x7fffu + ((u >> 16) & 1u)) >> 16;
}

__device__ __forceinline__ bf16x8 ldfragg(const uint* s, int idx) {
    return __builtin_bit_cast(bf16x8, *(const short8*)(s + idx));
}

// ------------------------------------------------- prep: zero ws + pack E-hi + ||e||^2
__global__ __launch_bounds__(256) void vq_prep(const float* __restrict__ embed,
                                               float* __restrict__ ws,
                                               uint* __restrict__ ehg,
                                               float* __restrict__ ee) {
    int t = threadIdx.x;
    int blk = blockIdx.x;
    for (int i = blk * 256 + t; i < WS_ZERO_FLOATS; i += 32 * 256) ws[i] = 0.f;

    int jl = t >> 4;           // 0..15
    int ci = t & 15;
    int j  = blk * 16 + jl;
    float nrm = 0.f;
    #pragma unroll
    for (int it = 0; it < 2; ++it) {
        int c2 = ci + it * 16;
        float x0 = embed[j * 64 + 2 * c2];
        float x1 = embed[j * 64 + 2 * c2 + 1];
        nrm = fmaf(x0, x0, nrm);
        nrm = fmaf(x1, x1, nrm);
        uint h0 = bf16rne(x0), h1 = bf16rne(x1);
        int plane = (c2 >> 4) * 4 + ((c2 >> 2) & 3);
        int idx = (j >> 7) * TB + plane * PS + (j & 127) * 4 + (c2 & 3);
        ehg[idx] = h0 | (h1 << 16);
    }
    #pragma unroll
    for (int off = 8; off > 0; off >>= 1) nrm += __shfl_xor(nrm, off, 16);
    if (ci == 0) ee[j] = nrm;
}

// ------------------------------------------------- MFMA argmax + exact rescore
// 2048 blocks x 256 threads; block = 64 points (region), wave = 16 points.
// No X staging: A-frags built from global; rescore re-reads input (L3-hot).
// LDS ~4 KB -> 8 blocks/CU -> 8 waves/SIMD (2x the old latency hiding).
__global__ __launch_bounds__(256, 8) void vq_argmax(
    const float* __restrict__ input, const uint* __restrict__ ehg,
    const float* __restrict__ ee, const float* __restrict__ embed,
    float* __restrict__ out_q, float* __restrict__ out_ids,
    int* __restrict__ ws_ids, float* __restrict__ ws) {
    __shared__ float sEE[512];
    __shared__ int sCand[128];
    __shared__ float sRes[128];
    __shared__ float cred[4];

    int t = threadIdx.x;
    int blk = blockIdx.x;
    int b = blk >> 6, region = blk & 63;    // region = 64 consecutive pixels (h=region)

    sEE[t] = ee[t];
    sEE[t + 256] = ee[t + 256];

    int l = t & 63, wv = t >> 6;
    int g = l >> 4, col = l & 15;
    int row = wv * 16 + col;                // point within block, 0..63

    const float* xg = input + (size_t)b * (EMB * HW) + region * 64;

    // A fragments (bf16-hi of X) straight from global: 8 channels each.
    bf16x8 Ah[2];
    #pragma unroll
    for (int kh = 0; kh < 2; ++kh) {
        int ch0 = kh * 32 + g * 8;
        uint4v fr;
        #pragma unroll
        for (int v = 0; v < 4; ++v) {
            float x0 = xg[(size_t)(ch0 + 2 * v) * HW + row];
            float x1 = xg[(size_t)(ch0 + 2 * v + 1) * HW + row];
            fr[v] = bf16rne(x0) | (bf16rne(x1) << 16);
        }
        Ah[kh] = __builtin_bit_cast(bf16x8, fr);
    }
    __syncthreads();   // sEE ready

    // per-lane PACKED top-2 (index in low 9 mantissa bits)
    float tb1[4], tb2[4];
    #pragma unroll
    for (int r = 0; r < 4; ++r) { tb1[r] = -3.0e38f; tb2[r] = -3.0e38f; }

    for (int jt = 0; jt < 4; ++jt) {
        const uint* eh = ehg + jt * TB;
        #pragma unroll
        for (int nt = 0; nt < 8; ++nt) {
            bf16x8 Bh0 = ldfragg(eh, (0 * 4 + g) * PS + (nt * 16 + col) * 4);
            bf16x8 Bh1 = ldfragg(eh, (1 * 4 + g) * PS + (nt * 16 + col) * 4);
            float e2 = -0.5f * sEE[jt * 128 + nt * 16 + col];
            f32x4 acc = {e2, e2, e2, e2};
            acc = __builtin_amdgcn_mfma_f32_16x16x32_bf16(Ah[0], Bh0, acc, 0, 0, 0);
            acc = __builtin_amdgcn_mfma_f32_16x16x32_bf16(Ah[1], Bh1, acc, 0, 0, 0);
            uint tag = (uint)(511 - (jt * 128 + nt * 16 + col));
            #pragma unroll
            for (int r = 0; r < 4; ++r) {
                float sp = __uint_as_float(
                    (__float_as_uint(acc[r]) & 0xFFFFFE00u) | tag);
                float o1 = tb1[r];
                tb1[r] = fmaxf(sp, o1);
                tb2[r] = __builtin_amdgcn_fmed3f(sp, o1, tb2[r]);
            }
        }
    }

    // 16-lane top-2 merge per point (packed); col==0 publishes codes
    #pragma unroll
    for (int r = 0; r < 4; ++r) {
        float t1 = tb1[r], t2 = tb2[r];
        #pragma unroll
        for (int off = 8; off > 0; off >>= 1) {
            float o1 = __shfl_xor(t1, off, 16);
            float o2 = __shfl_xor(t2, off, 16);
            float hi = fmaxf(t1, o1);
            float lo = fminf(t1, o1);
            t2 = fmaxf(lo, fmaxf(t2, o2));
            t1 = hi;
        }
        if (col == 0) {
            int p = wv * 16 + g * 4 + r;
            sCand[p * 2]     = 511 - (int)(__float_as_uint(t1) & 511u);
            sCand[p * 2 + 1] = 511 - (int)(__float_as_uint(t2) & 511u);
        }
    }
    __syncthreads();

    // ---- exact fp32 rescore of both candidates (threads t<128, 2 per point) ----
    int p = t & 63, wc = (t >> 6) & 1;
    int c = 0;
    if (t < 128) {
        c = sCand[p * 2 + wc];
        const v4f* erow = (const v4f*)(embed + c * 64);
        float dot = 0.f;
        #pragma unroll
        for (int plane = 0; plane < 16; ++plane) {
            v4f e4 = erow[plane];
            #pragma unroll
            for (int v = 0; v < 4; ++v) {
                float x = xg[(size_t)(plane * 4 + v) * HW + p];
                dot = fmaf(x, e4[v], dot);
            }
        }
        sRes[t] = fmaf(2.f, dot, -sEE[c]);
    }
    __syncthreads();

    float cl = 0.f;
    if (t < 128) {
        float sx = sRes[t];
        float so = sRes[t ^ 64];
        int co = sCand[p * 2 + (1 - wc)];
        bool win = (sx > so) || (sx == so && c < co);
        if (win) {
            // pixel = region*64 + p -> h = region, w = p
            ws_ids[b * HW + region * 64 + p] = c;              // natural order
            out_ids[b * HW + p * 64 + region] = (float)c;      // (b,w,h) quirk
            float* qg = out_q + (size_t)b * (EMB * HW) + region * 64 + p;
            const v4f* erow = (const v4f*)(embed + c * 64);
            #pragma unroll
            for (int plane = 0; plane < 16; ++plane) {
                v4f e4 = erow[plane];
                #pragma unroll
                for (int v = 0; v < 4; ++v) {
                    int ch = plane * 4 + v;
                    float x = xg[(size_t)ch * HW + p];
                    qg[(size_t)ch * HW] = e4[v];
                    float d = x - e4[v];
                    cl = fmaf(d, d, cl);
                }
            }
        }
    }
    #pragma unroll
    for (int off = 32; off > 0; off >>= 1) cl += __shfl_down(cl, off);
    if ((t & 63) == 0) cred[t >> 6] = cl;
    __syncthreads();
    if (t == 0)
        unsafeAtomicAdd(&ws[WS_COMMIT], (cred[0] + cred[1]) + (cred[2] + cred[3]));
}

// ------------------------------------------------- stats: esum + counts
// 1024 blocks = (b, 32 groups of 2 channels). LDS histogram in FIXED-POINT
// uint via native non-returning ds_add_u32 (float LDS atomics stall: R11).
__global__ __launch_bounds__(256) void vq_stats(
    const float* __restrict__ input, const int* __restrict__ ws_ids,
    float* __restrict__ ws) {
    __shared__ uint es[2 * 520];
    __shared__ uint cnt_s[DICT];

    int t = threadIdx.x;
    int bc = blockIdx.x;
    int b = bc >> 5, cg = bc & 31;

    #pragma unroll
    for (int i = t; i < 2 * 520; i += 256) es[i] = 0u;
    if (cg == 0)
        for (int i = t; i < DICT; i += 256) cnt_s[i] = 0u;

    const int* idg = ws_ids + b * HW;
    int4 idv[4];
    #pragma unroll
    for (int it = 0; it < 4; ++it)
        idv[it] = *(const int4*)(idg + (t + it * 256) * 4);
    __syncthreads();

    #pragma unroll
    for (int chl = 0; chl < 2; ++chl) {
        const float* xg = input + (size_t)b * (EMB * HW) + (size_t)(cg * 2 + chl) * HW;
        uint* esr = es + chl * 520;
        #pragma unroll
        for (int it = 0; it < 4; ++it) {
            v4f x = *(const v4f*)(xg + (t + it * 256) * 4);
            atomicAdd(&esr[idv[it].x], (uint)__float2int_rn(x.x * ESCALE));
            atomicAdd(&esr[idv[it].y], (uint)__float2int_rn(x.y * ESCALE));
            atomicAdd(&esr[idv[it].z], (uint)__float2int_rn(x.z * ESCALE));
            atomicAdd(&esr[idv[it].w], (uint)__float2int_rn(x.w * ESCALE));
        }
    }
    if (cg == 0) {
        #pragma unroll
        for (int it = 0; it < 4; ++it) {
            atomicAdd(&cnt_s[idv[it].x], 1u);
            atomicAdd(&cnt_s[idv[it].y], 1u);
            atomicAdd(&cnt_s[idv[it].z], 1u);
            atomicAdd(&cnt_s[idv[it].w], 1u);
        }
    }
    __syncthreads();

    #pragma unroll
    for (int i = t; i < 2 * DICT; i += 256) {
        int chl = i >> 9, j = i & 511;
        int v = (int)es[chl * 520 + j];
        if (v != 0)
            unsafeAtomicAdd(&ws[WS_ESUM + (cg * 2 + chl) * DICT + j],
                            (float)v * EINV);
    }
    if (cg == 0)
        for (int i = t; i < DICT; i += 256) {
            uint c = cnt_s[i];
            if (c != 0u) unsafeAtomicAdd(&ws[WS_COUNTS + i], (float)c);
        }
}

// ---------------------------------------------------- finalize (fused fin1+fin2)
__global__ __launch_bounds__(256) void vq_fin(
    const float* __restrict__ embed_avg, const float* __restrict__ cluster_size,
    const float* __restrict__ ws, float* __restrict__ out_embed,
    float* __restrict__ out_cs, float* __restrict__ out_avg,
    float* __restrict__ out_loss) {
    __shared__ float red[256];
    int t = threadIdx.x, blk = blockIdx.x;

    float ncs0 = cluster_size[t] * MOM + ws[WS_COUNTS + t] * OMOM;
    float ncs1 = cluster_size[t + 256] * MOM + ws[WS_COUNTS + t + 256] * OMOM;
    if (blk == 0) {
        out_cs[t] = ncs0;
        out_cs[t + 256] = ncs1;
        if (t == 0)
            out_loss[0] = ws[WS_COMMIT] * (1.0f / (float)((size_t)NPTS * EMB));
    }
    red[t] = ncs0 + ncs1;
    __syncthreads();
    #pragma unroll
    for (int off = 128; off > 0; off >>= 1) {
        if (t < off) red[t] += red[t + off];
        __syncthreads();
    }
    float n = red[0];

    int idx = blk * 256 + t;          // idx = ch*512 + d
    int ch = idx >> 9, d = idx & 511;
    float avg = embed_avg[idx] * MOM + ws[WS_ESUM + idx] * OMOM;
    out_avg[idx] = avg;
    float ncs = cluster_size[d] * MOM + ws[WS_COUNTS + d] * OMOM;
    float cs = n * (ncs + EPSV) / (n + (float)DICT * EPSV);
    out_embed[d * EMB + ch] = avg / cs;
}

extern "C" void kernel_launch(void* const* d_in, const int* in_sizes, int n_in,
                              void* d_out, int out_size, void* d_ws, size_t ws_size,
                              hipStream_t stream) {
    const float* input        = (const float*)d_in[0];
    const float* embed        = (const float*)d_in[1];
    const float* cluster_size = (const float*)d_in[2];
    const float* embed_avg    = (const float*)d_in[3];

    float* out   = (float*)d_out;
    float* q     = out;                         // 8388608
    float* loss  = out + 8388608;               // 1
    float* ids   = out + 8388609;               // 131072
    float* oemb  = out + 8519681;               // 32768
    float* ocs   = out + 8552449;               // 512
    float* oavg  = out + 8552961;               // 32768
    float* ws    = (float*)d_ws;

    vq_prep  <<<32, 256, 0, stream>>>(embed, ws, (uint*)(ws + WS_EHG), ws + WS_EE);
    vq_argmax<<<2048, 256, 0, stream>>>(input, (const uint*)(ws + WS_EHG),
                                        ws + WS_EE, embed, q, ids,
                                        (int*)(ws + WS_IDS), ws);
    vq_stats <<<1024, 256, 0, stream>>>(input, (const int*)(ws + WS_IDS), ws);
    vq_fin   <<<128, 256, 0, stream>>>(embed_avg, cluster_size, ws, oemb, ocs,
                                       oavg, loss);
}

// Round 15
// 79.146 us; speedup vs baseline: 1.0069x; 1.0069x over previous
//
#include <hip/hip_runtime.h>

#define EMB 64
#define DICT 512
#define HW 4096              // 64*64
#define NPTS (32 * HW)       // 131072
#define MOM 0.99f
#define OMOM 0.01f
#define EPSV 1e-5f

typedef float v4f __attribute__((ext_vector_type(4)));
typedef unsigned int uint;
typedef uint uint4v __attribute__((ext_vector_type(4)));
typedef short short8 __attribute__((ext_vector_type(8)));
typedef __bf16 bf16x8 __attribute__((ext_vector_type(8)));
typedef float f32x4 __attribute__((ext_vector_type(4)));

// ws layout (dword offsets)
#define WS_COMMIT 0
#define WS_COUNTS 64                      // 512
#define WS_ESUM   1024                    // 64*512
#define WS_ZERO_FLOATS 33792              // zeroed by vq_prep each call
#define WS_EE     33792                   // 512 (fp32 ||e||^2)
#define WS_EHG    34320                   // 4 tiles * 4160 (packed bf16-hi E)
#define WS_IDS    67600                   // 131072 ints (natural pixel order)

#define PS 520      // E plane stride in dwords: 130 rows x 4 dwords
#define TB 4160     // E tile blob: 8 planes (kh*4+g)
#define PSX 260     // X plane stride in dwords: 65 rows x 4 dwords (64 points)

#define ESCALE 65536.0f
#define EINV   (1.0f / 65536.0f)

__device__ __forceinline__ uint bf16rne(float x) {
    uint u = __float_as_uint(x);
    return (u + 0x7fffu + ((u >> 16) & 1u)) >> 16;
}

__device__ __forceinline__ bf16x8 ldfragg(const uint* s, int idx) {
    return __builtin_bit_cast(bf16x8, *(const short8*)(s + idx));
}

// ------------------------------------------------- prep: zero ws + pack E-hi + ||e||^2
__global__ __launch_bounds__(256) void vq_prep(const float* __restrict__ embed,
                                               float* __restrict__ ws,
                                               uint* __restrict__ ehg,
                                               float* __restrict__ ee) {
    int t = threadIdx.x;
    int blk = blockIdx.x;
    for (int i = blk * 256 + t; i < WS_ZERO_FLOATS; i += 32 * 256) ws[i] = 0.f;

    int jl = t >> 4;           // 0..15
    int ci = t & 15;
    int j  = blk * 16 + jl;
    float nrm = 0.f;
    #pragma unroll
    for (int it = 0; it < 2; ++it) {
        int c2 = ci + it * 16;
        float x0 = embed[j * 64 + 2 * c2];
        float x1 = embed[j * 64 + 2 * c2 + 1];
        nrm = fmaf(x0, x0, nrm);
        nrm = fmaf(x1, x1, nrm);
        uint h0 = bf16rne(x0), h1 = bf16rne(x1);
        int plane = (c2 >> 4) * 4 + ((c2 >> 2) & 3);
        int idx = (j >> 7) * TB + plane * PS + (j & 127) * 4 + (c2 & 3);
        ehg[idx] = h0 | (h1 << 16);
    }
    #pragma unroll
    for (int off = 8; off > 0; off >>= 1) nrm += __shfl_xor(nrm, off, 16);
    if (ci == 0) ee[j] = nrm;
}

// ------------------------------------------------- MFMA argmax + exact rescore
// 2048 blocks x 256 threads; block = 64 points (one h-row), 4 waves x 16 pts.
// X staged in ~17 KB LDS (single HBM fetch) -> 8 blocks/CU -> 32 waves/CU.
__global__ __launch_bounds__(256, 8) void vq_argmax(
    const float* __restrict__ input, const uint* __restrict__ ehg,
    const float* __restrict__ ee, const float* __restrict__ embed,
    float* __restrict__ out_q, float* __restrict__ out_ids,
    int* __restrict__ ws_ids, float* __restrict__ ws) {
    __shared__ float sX[16 * PSX];     // fp32: [plane=ch>>2][point][ch&3]
    __shared__ float sEE[512];
    __shared__ int sCand[128];
    __shared__ float sRes[128];
    __shared__ float cred[4];

    int t = threadIdx.x;
    int blk = blockIdx.x;
    int b = blk >> 6, h = blk & 63;

    const float* xg = input + (size_t)b * (EMB * HW) + h * 64;

    // ---- stage X: thread (pg = t>>6) handles planes pg*4..pg*4+3, point t&63 ----
    {
        int p = t & 63;
        int pg = t >> 6;
        #pragma unroll
        for (int i = 0; i < 4; ++i) {
            int plane = pg * 4 + i;
            v4f v;
            #pragma unroll
            for (int c = 0; c < 4; ++c)
                v[c] = xg[(size_t)(plane * 4 + c) * HW + p];
            *(v4f*)&sX[plane * PSX + p * 4] = v;
        }
        sEE[t] = ee[t];
        sEE[t + 256] = ee[t + 256];
    }
    __syncthreads();

    int l = t & 63, wv = t >> 6;
    int g = l >> 4, col = l & 15;
    int row = wv * 16 + col;               // point 0..63

    // A fragments (bf16-hi of X) from LDS
    bf16x8 Ah[2];
    #pragma unroll
    for (int kh = 0; kh < 2; ++kh) {
        int p0 = kh * 8 + g * 2;
        v4f xa = *(const v4f*)&sX[p0 * PSX + row * 4];
        v4f xb = *(const v4f*)&sX[(p0 + 1) * PSX + row * 4];
        uint4v fr;
        fr[0] = bf16rne(xa[0]) | (bf16rne(xa[1]) << 16);
        fr[1] = bf16rne(xa[2]) | (bf16rne(xa[3]) << 16);
        fr[2] = bf16rne(xb[0]) | (bf16rne(xb[1]) << 16);
        fr[3] = bf16rne(xb[2]) | (bf16rne(xb[3]) << 16);
        Ah[kh] = __builtin_bit_cast(bf16x8, fr);
    }

    // per-lane PACKED top-2 (index in low 9 mantissa bits)
    float tb1[4], tb2[4];
    #pragma unroll
    for (int r = 0; r < 4; ++r) { tb1[r] = -3.0e38f; tb2[r] = -3.0e38f; }

    for (int jt = 0; jt < 4; ++jt) {
        const uint* eh = ehg + jt * TB;
        #pragma unroll
        for (int nt = 0; nt < 8; ++nt) {
            bf16x8 Bh0 = ldfragg(eh, (0 * 4 + g) * PS + (nt * 16 + col) * 4);
            bf16x8 Bh1 = ldfragg(eh, (1 * 4 + g) * PS + (nt * 16 + col) * 4);
            float e2 = -0.5f * sEE[jt * 128 + nt * 16 + col];
            f32x4 acc = {e2, e2, e2, e2};
            acc = __builtin_amdgcn_mfma_f32_16x16x32_bf16(Ah[0], Bh0, acc, 0, 0, 0);
            acc = __builtin_amdgcn_mfma_f32_16x16x32_bf16(Ah[1], Bh1, acc, 0, 0, 0);
            uint tag = (uint)(511 - (jt * 128 + nt * 16 + col));
            #pragma unroll
            for (int r = 0; r < 4; ++r) {
                float sp = __uint_as_float(
                    (__float_as_uint(acc[r]) & 0xFFFFFE00u) | tag);
                float o1 = tb1[r];
                tb1[r] = fmaxf(sp, o1);
                tb2[r] = __builtin_amdgcn_fmed3f(sp, o1, tb2[r]);
            }
        }
    }

    // 16-lane top-2 merge per point (packed); col==0 publishes codes
    #pragma unroll
    for (int r = 0; r < 4; ++r) {
        float t1 = tb1[r], t2 = tb2[r];
        #pragma unroll
        for (int off = 8; off > 0; off >>= 1) {
            float o1 = __shfl_xor(t1, off, 16);
            float o2 = __shfl_xor(t2, off, 16);
            float hi = fmaxf(t1, o1);
            float lo = fminf(t1, o1);
            t2 = fmaxf(lo, fmaxf(t2, o2));
            t1 = hi;
        }
        if (col == 0) {
            int p = wv * 16 + g * 4 + r;
            sCand[p * 2]     = 511 - (int)(__float_as_uint(t1) & 511u);
            sCand[p * 2 + 1] = 511 - (int)(__float_as_uint(t2) & 511u);
        }
    }
    __syncthreads();

    // ---- exact fp32 rescore of both candidates (t<128, 2 per point) ----
    int p = t & 63, wc = (t >> 6) & 1;
    int c = 0;
    if (t < 128) {
        c = sCand[p * 2 + wc];
        const v4f* erow = (const v4f*)(embed + c * 64);
        float dot = 0.f;
        #pragma unroll
        for (int plane = 0; plane < 16; ++plane) {
            v4f xq = *(const v4f*)&sX[plane * PSX + p * 4];
            v4f e4 = erow[plane];
            dot = fmaf(xq[0], e4[0], dot);
            dot = fmaf(xq[1], e4[1], dot);
            dot = fmaf(xq[2], e4[2], dot);
            dot = fmaf(xq[3], e4[3], dot);
        }
        sRes[t] = fmaf(2.f, dot, -sEE[c]);
    }
    __syncthreads();

    float cl = 0.f;
    if (t < 128) {
        float sx = sRes[t];
        float so = sRes[t ^ 64];
        int co = sCand[p * 2 + (1 - wc)];
        bool win = (sx > so) || (sx == so && c < co);
        if (win) {
            ws_ids[b * HW + h * 64 + p] = c;               // natural order
            out_ids[b * HW + p * 64 + h] = (float)c;       // (b,w,h) quirk
            float* qg = out_q + (size_t)b * (EMB * HW) + h * 64 + p;
            const v4f* erow = (const v4f*)(embed + c * 64);
            #pragma unroll
            for (int plane = 0; plane < 16; ++plane) {
                v4f xq = *(const v4f*)&sX[plane * PSX + p * 4];
                v4f e4 = erow[plane];
                #pragma unroll
                for (int v = 0; v < 4; ++v) {
                    int ch = plane * 4 + v;
                    qg[(size_t)ch * HW] = e4[v];
                    float d = xq[v] - e4[v];
                    cl = fmaf(d, d, cl);
                }
            }
        }
    }
    #pragma unroll
    for (int off = 32; off > 0; off >>= 1) cl += __shfl_down(cl, off);
    if ((t & 63) == 0) cred[t >> 6] = cl;
    __syncthreads();
    if (t == 0)
        unsafeAtomicAdd(&ws[WS_COMMIT], (cred[0] + cred[1]) + (cred[2] + cred[3]));
}

// ------------------------------------------------- stats: esum + counts
// 1024 blocks = (b, 32 groups of 2 channels). LDS histogram in FIXED-POINT
// uint via native non-returning ds_add_u32 (float LDS atomics stall: R11).
__global__ __launch_bounds__(256) void vq_stats(
    const float* __restrict__ input, const int* __restrict__ ws_ids,
    float* __restrict__ ws) {
    __shared__ uint es[2 * 520];
    __shared__ uint cnt_s[DICT];

    int t = threadIdx.x;
    int bc = blockIdx.x;
    int b = bc >> 5, cg = bc & 31;

    #pragma unroll
    for (int i = t; i < 2 * 520; i += 256) es[i] = 0u;
    if (cg == 0)
        for (int i = t; i < DICT; i += 256) cnt_s[i] = 0u;

    const int* idg = ws_ids + b * HW;
    int4 idv[4];
    #pragma unroll
    for (int it = 0; it < 4; ++it)
        idv[it] = *(const int4*)(idg + (t + it * 256) * 4);
    __syncthreads();

    #pragma unroll
    for (int chl = 0; chl < 2; ++chl) {
        const float* xg = input + (size_t)b * (EMB * HW) + (size_t)(cg * 2 + chl) * HW;
        uint* esr = es + chl * 520;
        #pragma unroll
        for (int it = 0; it < 4; ++it) {
            v4f x = *(const v4f*)(xg + (t + it * 256) * 4);
            atomicAdd(&esr[idv[it].x], (uint)__float2int_rn(x.x * ESCALE));
            atomicAdd(&esr[idv[it].y], (uint)__float2int_rn(x.y * ESCALE));
            atomicAdd(&esr[idv[it].z], (uint)__float2int_rn(x.z * ESCALE));
            atomicAdd(&esr[idv[it].w], (uint)__float2int_rn(x.w * ESCALE));
        }
    }
    if (cg == 0) {
        #pragma unroll
        for (int it = 0; it < 4; ++it) {
            atomicAdd(&cnt_s[idv[it].x], 1u);
            atomicAdd(&cnt_s[idv[it].y], 1u);
            atomicAdd(&cnt_s[idv[it].z], 1u);
            atomicAdd(&cnt_s[idv[it].w], 1u);
        }
    }
    __syncthreads();

    #pragma unroll
    for (int i = t; i < 2 * DICT; i += 256) {
        int chl = i >> 9, j = i & 511;
        int v = (int)es[chl * 520 + j];
        if (v != 0)
            unsafeAtomicAdd(&ws[WS_ESUM + (cg * 2 + chl) * DICT + j],
                            (float)v * EINV);
    }
    if (cg == 0)
        for (int i = t; i < DICT; i += 256) {
            uint c = cnt_s[i];
            if (c != 0u) unsafeAtomicAdd(&ws[WS_COUNTS + i], (float)c);
        }
}

// ---------------------------------------------------- finalize (fused fin1+fin2)
__global__ __launch_bounds__(256) void vq_fin(
    const float* __restrict__ embed_avg, const float* __restrict__ cluster_size,
    const float* __restrict__ ws, float* __restrict__ out_embed,
    float* __restrict__ out_cs, float* __restrict__ out_avg,
    float* __restrict__ out_loss) {
    __shared__ float red[256];
    int t = threadIdx.x, blk = blockIdx.x;

    float ncs0 = cluster_size[t] * MOM + ws[WS_COUNTS + t] * OMOM;
    float ncs1 = cluster_size[t + 256] * MOM + ws[WS_COUNTS + t + 256] * OMOM;
    if (blk == 0) {
        out_cs[t] = ncs0;
        out_cs[t + 256] = ncs1;
        if (t == 0)
            out_loss[0] = ws[WS_COMMIT] * (1.0f / (float)((size_t)NPTS * EMB));
    }
    red[t] = ncs0 + ncs1;
    __syncthreads();
    #pragma unroll
    for (int off = 128; off > 0; off >>= 1) {
        if (t < off) red[t] += red[t + off];
        __syncthreads();
    }
    float n = red[0];

    int idx = blk * 256 + t;          // idx = ch*512 + d
    int ch = idx >> 9, d = idx & 511;
    float avg = embed_avg[idx] * MOM + ws[WS_ESUM + idx] * OMOM;
    out_avg[idx] = avg;
    float ncs = cluster_size[d] * MOM + ws[WS_COUNTS + d] * OMOM;
    float cs = n * (ncs + EPSV) / (n + (float)DICT * EPSV);
    out_embed[d * EMB + ch] = avg / cs;
}

extern "C" void kernel_launch(void* const* d_in, const int* in_sizes, int n_in,
                              void* d_out, int out_size, void* d_ws, size_t ws_size,
                              hipStream_t stream) {
    const float* input        = (const float*)d_in[0];
    const float* embed        = (const float*)d_in[1];
    const float* cluster_size = (const float*)d_in[2];
    const float* embed_avg    = (const float*)d_in[3];

    float* out   = (float*)d_out;
    float* q     = out;                         // 8388608
    float* loss  = out + 8388608;               // 1
    float* ids   = out + 8388609;               // 131072
    float* oemb  = out + 8519681;               // 32768
    float* ocs   = out + 8552449;               // 512
    float* oavg  = out + 8552961;               // 32768
    float* ws    = (float*)d_ws;

    vq_prep  <<<32, 256, 0, stream>>>(embed, ws, (uint*)(ws + WS_EHG), ws + WS_EE);
    vq_argmax<<<2048, 256, 0, stream>>>(input, (const uint*)(ws + WS_EHG),
                                        ws + WS_EE, embed, q, ids,
                                        (int*)(ws + WS_IDS), ws);
    vq_stats <<<1024, 256, 0, stream>>>(input, (const int*)(ws + WS_IDS), ws);
    vq_fin   <<<128, 256, 0, stream>>>(embed_avg, cluster_size, ws, oemb, ocs,
                                       oavg, loss);
}